// Round 17
// baseline (56.913 us; speedup 1.0000x reference)
//
#include <hip/hip_runtime.h>
#include <hip/hip_bf16.h>
#include <math.h>

#define NN 512
#define HH 128
#define FF 32
#define RR 8
#define EPSV 0.1f
#define INV_EPS 10.0f
#define LOG2E 1.4426950408889634f
#define LN2 0.6931471805599453f
#define K2E (INV_EPS * LOG2E)   // exp(x*INV_EPS) = exp2(x*K2E)

// minimax-ish coeffs for log2(1+u), u in (0,1], err <= ~2e-4, P(0)=0
#define PC1 1.437284f
#define PC2 (-0.672862f)
#define PC3 0.315362f
#define PC4 (-0.0799600f)

typedef unsigned short ushort_t;
typedef __attribute__((ext_vector_type(8))) short bf16x8;
typedef __attribute__((ext_vector_type(4))) float f32x4;
typedef __attribute__((ext_vector_type(4))) unsigned int u32x4;
typedef __attribute__((ext_vector_type(2))) unsigned int u32x2;

// base-2 softplus, 1 transcendental: g(t) = max(t,0) + poly(2^-|t|)
__device__ __forceinline__ float g2(float t) {
    const float u = __builtin_amdgcn_exp2f(-fabsf(t));
    const float p = u * (PC1 + u * (PC2 + u * (PC3 + u * PC4)));
    return fmaxf(t, 0.f) + p;
}
__device__ __forceinline__ ushort_t f2b(float f) {  // fp32 -> bf16 RNE
    unsigned u = __float_as_uint(f);
    return (ushort_t)((u + 0x7fffu + ((u >> 16) & 1u)) >> 16);
}
__device__ __forceinline__ float b2f(ushort_t h) {
    return __uint_as_float(((unsigned)h) << 16);
}
__device__ __forceinline__ unsigned pk2(float a, float b) {  // 2x fp32 -> packed bf16x2
    __hip_bfloat162 h = __float22bfloat162_rn(make_float2(a, b));
    return *reinterpret_cast<unsigned*>(&h);
}

// ---- K0 prep: Wt bf16 W^T (unscaled); XWxb=(X@Wx+b0)*log2e, YWyb=(Y@Wy)*log2e (bf16);
//      b1e=b1*log2e, b2e=b2*log2e, WoutE=Wout*ln2 (fp32) ----
__global__ __launch_bounds__(256) void prep_kernel(
    const float* __restrict__ X, const float* __restrict__ Y,
    const float* __restrict__ Wx, const float* __restrict__ Wy,
    const float* __restrict__ b0, const float* __restrict__ W1, const float* __restrict__ W2,
    const float* __restrict__ b1, const float* __restrict__ b2, const float* __restrict__ Wout,
    ushort_t* __restrict__ Wt1b, ushort_t* __restrict__ Wt2b,
    ushort_t* __restrict__ XWxb, ushort_t* __restrict__ YWyb,
    float* __restrict__ b1e, float* __restrict__ b2e, float* __restrict__ WoutE) {
    int gid = blockIdx.x * 256 + threadIdx.x;
    if (gid < 32768) {
        int sel = gid >> 14;
        int idx = gid & 16383;                  // n*128 + k
        int n = idx >> 7, k = idx & 127;
        (sel ? Wt2b : Wt1b)[idx] = f2b((sel ? W2 : W1)[k * HH + n]);
    } else if (gid < 98304) {
        int g = gid - 32768;
        int i = g >> 7, h = g & 127;
        float s = b0[h];
#pragma unroll
        for (int f = 0; f < FF; ++f) s += X[i * FF + f] * Wx[f * HH + h];
        XWxb[g] = f2b(s * LOG2E);
    } else if (gid < 163840) {
        int g = gid - 98304;
        int i = g >> 7, h = g & 127;
        float s = 0.f;
#pragma unroll
        for (int r = 0; r < RR; ++r) s += Y[i * RR + r] * Wy[r * HH + h];
        YWyb[g] = f2b(s * LOG2E);
    } else if (gid < 163968) {
        b1e[gid - 163840] = b1[gid - 163840] * LOG2E;
    } else if (gid < 164096) {
        b2e[gid - 163968] = b2[gid - 163968] * LOG2E;
    } else if (gid < 164224) {
        WoutE[gid - 164096] = Wout[gid - 164096] * LN2;
    }
}

// ---- K1: one block per (i, 128-j chunk); 512 threads / 8 waves; in-place H tile.
// Wave wv: h-quarter hq = wv&3, j-half jh = wv>>2. Per-thread work identical to R16. ----
__global__ __launch_bounds__(512) void pair_kernel(
    const ushort_t* __restrict__ XWxb, const ushort_t* __restrict__ YWyb,
    const ushort_t* __restrict__ Wt1b, const ushort_t* __restrict__ Wt2b,
    const float* __restrict__ U, const float* __restrict__ Y,
    const float* __restrict__ b1e, const float* __restrict__ b2e,
    const float* __restrict__ WoutE, const float* __restrict__ bout,
    float* __restrict__ psi_arr, float* __restrict__ Mp, float* __restrict__ Sp) {
    __shared__ ushort_t Hs[128 * HH];   // 32 KB, holds H0 then (in-place) H1
    __shared__ float psum[2][4][64];    // [j-half][h-quarter][j] 2 KB

    const int i = blockIdx.x;
    const int q = blockIdx.y;           // 128-j chunk index 0..3
    const int j0 = q * 128;
    const int t = threadIdx.x;
    const int wv = t >> 6;              // 0..7
    const int hq = wv & 3;              // h-quarter
    const int jh = wv >> 2;             // j-half
    const int jbase = jh * 64;
    const int r16 = t & 15;
    const int g4 = (t >> 4) & 3;
    const int srow = t >> 4;            // 0..31 (staging row group)
    const float boutv = bout[0];

    // per-thread slice of XWx_i (+b0, *log2e), cols r16*8..+7
    float axf[8];
    {
        bf16x8 axv = *(const bf16x8*)&XWxb[i * HH + r16 * 8];
#pragma unroll
        for (int e = 0; e < 8; ++e) axf[e] = b2f((ushort_t)axv[e]);
    }
    // cost dot for this lane's j (used by t<128 in LSE phase)
    float cost;
    {
        const int j = j0 + (t & 127);
        const float4 u0 = *(const float4*)&U[i * RR];
        const float4 u1 = *(const float4*)&U[i * RR + 4];
        const float4 y0 = *(const float4*)&Y[j * RR];
        const float4 y1 = *(const float4*)&Y[j * RR + 4];
        cost = u0.x * y0.x + u0.y * y0.y + u0.z * y0.z + u0.w * y0.w +
               u1.x * y1.x + u1.y * y1.y + u1.z * y1.z + u1.w * y1.w;
    }
    // hoisted layer-1 weight fragments + bias (wave owns h in [hq*32,+32))
    bf16x8 afr1[2][4];
#pragma unroll
    for (int mt = 0; mt < 2; ++mt)
#pragma unroll
        for (int ks = 0; ks < 4; ++ks)
            afr1[mt][ks] = *(const bf16x8*)&Wt1b[(hq * 32 + mt * 16 + r16) * HH + ks * 32 + g4 * 8];
    float4 bias1h[2];
    bias1h[0] = *(const float4*)&b1e[hq * 32 + g4 * 4];
    bias1h[1] = *(const float4*)&b1e[hq * 32 + 16 + g4 * 4];
    float4 woutr[2];
    woutr[0] = *(const float4*)&WoutE[hq * 32 + g4 * 4];
    woutr[1] = *(const float4*)&WoutE[hq * 32 + 16 + g4 * 4];

    // ---- stage H0 = g2(axf + YWy[j]) bf16, XOR-swizzled (128 rows) ----
#pragma unroll
    for (int s = 0; s < 4; ++s) {
        const int p = s * 32 + srow;
        bf16x8 yv = *(const bf16x8*)&YWyb[(j0 + p) * HH + r16 * 8];
        unsigned pk[4];
#pragma unroll
        for (int e = 0; e < 4; ++e) {
            float v0 = g2(axf[2 * e]     + b2f((ushort_t)yv[2 * e]));
            float v1 = g2(axf[2 * e + 1] + b2f((ushort_t)yv[2 * e + 1]));
            pk[e] = pk2(v0, v1);
        }
        *(u32x4*)&Hs[p * HH + ((r16 ^ (p & 7)) << 3)] = *(u32x4*)pk;
    }
    __syncthreads();                    // A: H0 ready

    // ---- layer 1 (h-owned, hoisted weights): t1 = W1t @ g(t0) + b1e ----
    f32x4 acc[2][4];
#pragma unroll
    for (int mt = 0; mt < 2; ++mt)
#pragma unroll
        for (int nt = 0; nt < 4; ++nt) {
            acc[mt][nt][0] = bias1h[mt].x; acc[mt][nt][1] = bias1h[mt].y;
            acc[mt][nt][2] = bias1h[mt].z; acc[mt][nt][3] = bias1h[mt].w;
        }
#pragma unroll
    for (int ks = 0; ks < 4; ++ks) {
        const int kb = ks * 32 + g4 * 8;
#pragma unroll
        for (int nt = 0; nt < 4; ++nt) {
            const int j = jbase + nt * 16 + r16;
            bf16x8 bfr = *(const bf16x8*)&Hs[j * HH + (kb ^ ((j & 7) << 3))];
            acc[0][nt] = __builtin_amdgcn_mfma_f32_16x16x32_bf16(afr1[0][ks], bfr, acc[0][nt], 0, 0, 0);
            acc[1][nt] = __builtin_amdgcn_mfma_f32_16x16x32_bf16(afr1[1][ks], bfr, acc[1][nt], 0, 0, 0);
        }
    }
    __syncthreads();                    // R: all H0 reads retired -> safe to overwrite

    // store H1[j][h1] = g2(t1) bf16 swizzled IN-PLACE (4 consecutive h1 -> b64)
#pragma unroll
    for (int mt = 0; mt < 2; ++mt) {
        const int hb = hq * 32 + mt * 16 + g4 * 4;
#pragma unroll
        for (int nt = 0; nt < 4; ++nt) {
            const int j = jbase + nt * 16 + r16;
            u32x2 wv2;
            wv2[0] = pk2(g2(acc[mt][nt][0]), g2(acc[mt][nt][1]));
            wv2[1] = pk2(g2(acc[mt][nt][2]), g2(acc[mt][nt][3]));
            *(u32x2*)&Hs[j * HH + (hb ^ ((j & 7) << 3))] = wv2;
        }
    }
    __syncthreads();                    // X: H1 ready

    // ---- layer 2 (h-owned, batch loads): t2 = W2t @ g(t1) + b2e ----
    {
        const int hbase = hq * 32 + g4 * 4;
#pragma unroll
        for (int mt = 0; mt < 2; ++mt) {
            float4 bb = *(const float4*)&b2e[hbase + mt * 16];
#pragma unroll
            for (int nt = 0; nt < 4; ++nt) {
                acc[mt][nt][0] = bb.x; acc[mt][nt][1] = bb.y;
                acc[mt][nt][2] = bb.z; acc[mt][nt][3] = bb.w;
            }
        }
        bf16x8 afr2[2][4];
#pragma unroll
        for (int mt = 0; mt < 2; ++mt)
#pragma unroll
            for (int ks = 0; ks < 4; ++ks)
                afr2[mt][ks] = *(const bf16x8*)&Wt2b[(hq * 32 + mt * 16 + r16) * HH + ks * 32 + g4 * 8];
#pragma unroll
        for (int ks = 0; ks < 4; ++ks) {
            const int kb = ks * 32 + g4 * 8;
#pragma unroll
            for (int nt = 0; nt < 4; ++nt) {
                const int j = jbase + nt * 16 + r16;
                bf16x8 bfr = *(const bf16x8*)&Hs[j * HH + (kb ^ ((j & 7) << 3))];
                acc[0][nt] = __builtin_amdgcn_mfma_f32_16x16x32_bf16(afr2[0][ks], bfr, acc[0][nt], 0, 0, 0);
                acc[1][nt] = __builtin_amdgcn_mfma_f32_16x16x32_bf16(afr2[1][ks], bfr, acc[1][nt], 0, 0, 0);
            }
        }
    }
    // ---- epilogue in-register: psi partial -> psum[jh][hq] ----
    {
        float part[4] = {0.f, 0.f, 0.f, 0.f};
#pragma unroll
        for (int mt = 0; mt < 2; ++mt) {
            const float wr[4] = {woutr[mt].x, woutr[mt].y, woutr[mt].z, woutr[mt].w};
#pragma unroll
            for (int r = 0; r < 4; ++r) {
                const float wgt = wr[r];
#pragma unroll
                for (int nt = 0; nt < 4; ++nt)
                    part[nt] += g2(acc[mt][nt][r]) * wgt;
            }
        }
#pragma unroll
        for (int nt = 0; nt < 4; ++nt) {
            part[nt] += __shfl_xor(part[nt], 16);
            part[nt] += __shfl_xor(part[nt], 32);
        }
        if (g4 == 0) {
#pragma unroll
            for (int nt = 0; nt < 4; ++nt) psum[jh][hq][nt * 16 + r16] = part[nt];
        }
    }
    __syncthreads();                    // F: psum ready

    // ---- LSE partial (t<128 lanes, one j each; two waves reduce independently) ----
    if (t < 128) {
        const int jh2 = t >> 6;
        const int jl = t & 63;
        const float psi = boutv + psum[jh2][0][jl] + psum[jh2][1][jl] +
                          psum[jh2][2][jl] + psum[jh2][3][jl];
        const int j = j0 + t;
        if (j == i) psi_arr[i] = psi;
        const float sv = cost - psi;
        float M = sv;
#pragma unroll
        for (int o = 1; o < 64; o <<= 1) M = fmaxf(M, __shfl_xor(M, o));
        float S = __builtin_amdgcn_exp2f((sv - M) * K2E);
#pragma unroll
        for (int o = 1; o < 64; o <<= 1) S += __shfl_xor(S, o);
        if (jl == 0) {
            Mp[i * 8 + q * 2 + jh2] = M;
            Sp[i * 8 + q * 2 + jh2] = S;
        }
    }
}

// ---- K2: combine 8 partials per i -> phi_i; total = mean(phi) + mean(psi) ----
__global__ __launch_bounds__(512) void finalize_kernel(
    const float* __restrict__ psi_arr, const float* __restrict__ Mp,
    const float* __restrict__ Sp, float* __restrict__ out) {
    __shared__ float red[8];
    const int t = threadIdx.x;  // = i
    float Mq[8], Sq[8];
#pragma unroll
    for (int q = 0; q < 8; ++q) { Mq[q] = Mp[t * 8 + q]; Sq[q] = Sp[t * 8 + q]; }
    float Mg = Mq[0];
#pragma unroll
    for (int q = 1; q < 8; ++q) Mg = fmaxf(Mg, Mq[q]);
    float S = 0.f;
#pragma unroll
    for (int q = 0; q < 8; ++q) S += Sq[q] * __builtin_amdgcn_exp2f((Mq[q] - Mg) * K2E);
    const float phi = EPSV * (__logf(S) - __logf((float)NN)) + Mg;
    float v = phi + psi_arr[t];
#pragma unroll
    for (int o = 1; o < 64; o <<= 1) v += __shfl_xor(v, o);
    if ((t & 63) == 0) red[t >> 6] = v;
    __syncthreads();
    if (t == 0) {
        float tot = 0.f;
#pragma unroll
        for (int w = 0; w < 8; ++w) tot += red[w];
        out[0] = tot / (float)NN;
    }
}

extern "C" void kernel_launch(void* const* d_in, const int* in_sizes, int n_in,
                              void* d_out, int out_size, void* d_ws, size_t ws_size,
                              hipStream_t stream) {
    (void)in_sizes; (void)n_in; (void)out_size; (void)ws_size;
    const float* X    = (const float*)d_in[0];
    const float* U    = (const float*)d_in[1];
    const float* Y    = (const float*)d_in[2];
    const float* Wx   = (const float*)d_in[3];
    const float* Wy   = (const float*)d_in[4];
    const float* b0   = (const float*)d_in[5];
    const float* W1   = (const float*)d_in[6];
    const float* b1   = (const float*)d_in[7];
    const float* W2   = (const float*)d_in[8];
    const float* b2   = (const float*)d_in[9];
    const float* Wout = (const float*)d_in[10];
    const float* bout = (const float*)d_in[11];
    float* out = (float*)d_out;

    char* ws = (char*)d_ws;
    ushort_t* Wt1b    = (ushort_t*)(ws);                   // 32 KB
    ushort_t* Wt2b    = (ushort_t*)(ws + 32768);           // 32 KB
    ushort_t* XWxb    = (ushort_t*)(ws + 65536);           // 128 KB
    ushort_t* YWyb    = (ushort_t*)(ws + 196608);          // 128 KB
    float*    psi_arr = (float*)(ws + 327680);             // 2 KB
    float*    Mp      = (float*)(ws + 329728);             // 16 KB
    float*    Sp      = (float*)(ws + 346112);             // 16 KB
    float*    b1e     = (float*)(ws + 362496);             // 512 B
    float*    b2e     = (float*)(ws + 363008);             // 512 B
    float*    WoutE   = (float*)(ws + 363520);             // 512 B

    prep_kernel<<<642, 256, 0, stream>>>(X, Y, Wx, Wy, b0, W1, W2, b1, b2, Wout,
                                         Wt1b, Wt2b, XWxb, YWyb, b1e, b2e, WoutE);
    pair_kernel<<<dim3(NN, 4), 512, 0, stream>>>(XWxb, YWyb, Wt1b, Wt2b, U, Y,
                                                 b1e, b2e, WoutE, bout, psi_arr, Mp, Sp);
    finalize_kernel<<<1, 512, 0, stream>>>(psi_arr, Mp, Sp, out);
}

// Round 18
// 51.461 us; speedup vs baseline: 1.1059x; 1.1059x over previous
//
#include <hip/hip_runtime.h>
#include <hip/hip_bf16.h>
#include <math.h>

#define NN 512
#define HH 128
#define FF 32
#define RR 8
#define EPSV 0.1f
#define INV_EPS 10.0f
#define LOG2E 1.4426950408889634f
#define LN2 0.6931471805599453f
#define K2E (INV_EPS * LOG2E)   // exp(x*INV_EPS) = exp2(x*K2E)

// minimax-ish coeffs for log2(1+u), u in (0,1], err <= ~2e-4, P(0)=0
#define PC1 1.437284f
#define PC2 (-0.672862f)
#define PC3 0.315362f
#define PC4 (-0.0799600f)

typedef unsigned short ushort_t;
typedef __attribute__((ext_vector_type(8))) short bf16x8;
typedef __attribute__((ext_vector_type(4))) float f32x4;
typedef __attribute__((ext_vector_type(4))) unsigned int u32x4;
typedef __attribute__((ext_vector_type(2))) unsigned int u32x2;

// base-2 softplus, 1 transcendental: g(t) = max(t,0) + poly(2^-|t|)
__device__ __forceinline__ float g2(float t) {
    const float u = __builtin_amdgcn_exp2f(-fabsf(t));
    const float p = u * (PC1 + u * (PC2 + u * (PC3 + u * PC4)));
    return fmaxf(t, 0.f) + p;
}
__device__ __forceinline__ ushort_t f2b(float f) {  // fp32 -> bf16 RNE
    unsigned u = __float_as_uint(f);
    return (ushort_t)((u + 0x7fffu + ((u >> 16) & 1u)) >> 16);
}
__device__ __forceinline__ float b2f(ushort_t h) {
    return __uint_as_float(((unsigned)h) << 16);
}
__device__ __forceinline__ unsigned pk2(float a, float b) {  // 2x fp32 -> packed bf16x2
    __hip_bfloat162 h = __float22bfloat162_rn(make_float2(a, b));
    return *reinterpret_cast<unsigned*>(&h);
}

// ---- K0 prep: Wt bf16 W^T (unscaled); XWxb=(X@Wx+b0)*log2e, YWyb=(Y@Wy)*log2e (bf16);
//      b1e=b1*log2e, b2e=b2*log2e, WoutE=Wout*ln2 (fp32) ----
__global__ __launch_bounds__(256) void prep_kernel(
    const float* __restrict__ X, const float* __restrict__ Y,
    const float* __restrict__ Wx, const float* __restrict__ Wy,
    const float* __restrict__ b0, const float* __restrict__ W1, const float* __restrict__ W2,
    const float* __restrict__ b1, const float* __restrict__ b2, const float* __restrict__ Wout,
    ushort_t* __restrict__ Wt1b, ushort_t* __restrict__ Wt2b,
    ushort_t* __restrict__ XWxb, ushort_t* __restrict__ YWyb,
    float* __restrict__ b1e, float* __restrict__ b2e, float* __restrict__ WoutE) {
    int gid = blockIdx.x * 256 + threadIdx.x;
    if (gid < 32768) {
        int sel = gid >> 14;
        int idx = gid & 16383;                  // n*128 + k
        int n = idx >> 7, k = idx & 127;
        (sel ? Wt2b : Wt1b)[idx] = f2b((sel ? W2 : W1)[k * HH + n]);
    } else if (gid < 98304) {
        int g = gid - 32768;
        int i = g >> 7, h = g & 127;
        float s = b0[h];
#pragma unroll
        for (int f = 0; f < FF; ++f) s += X[i * FF + f] * Wx[f * HH + h];
        XWxb[g] = f2b(s * LOG2E);
    } else if (gid < 163840) {
        int g = gid - 98304;
        int i = g >> 7, h = g & 127;
        float s = 0.f;
#pragma unroll
        for (int r = 0; r < RR; ++r) s += Y[i * RR + r] * Wy[r * HH + h];
        YWyb[g] = f2b(s * LOG2E);
    } else if (gid < 163968) {
        b1e[gid - 163840] = b1[gid - 163840] * LOG2E;
    } else if (gid < 164096) {
        b2e[gid - 163968] = b2[gid - 163968] * LOG2E;
    } else if (gid < 164224) {
        WoutE[gid - 164096] = Wout[gid - 164096] * LN2;
    }
}

// ---- K1: one block per (i, pair of 64-j chunks); two interleaved ILP streams ----
__global__ void pair_kernel(
    const ushort_t* __restrict__ XWxb, const ushort_t* __restrict__ YWyb,
    const ushort_t* __restrict__ Wt1b, const ushort_t* __restrict__ Wt2b,
    const float* __restrict__ U, const float* __restrict__ Y,
    const float* __restrict__ b1e, const float* __restrict__ b2e,
    const float* __restrict__ WoutE, const float* __restrict__ bout,
    float* __restrict__ psi_arr, float* __restrict__ Mp, float* __restrict__ Sp) {
    __shared__ ushort_t HsA[64 * HH];   // 16 KB, stream A: H0 then in-place H1
    __shared__ ushort_t HsB[64 * HH];   // 16 KB, stream B
    __shared__ float psum[2][4][64];    // [stream][h-quarter][j] 2 KB

    const int i = blockIdx.x;
    const int q = blockIdx.y;           // chunk-pair 0..3
    const int j0a = q * 128;            // stream A chunk base
    const int j0b = q * 128 + 64;       // stream B chunk base
    const int t = threadIdx.x;
    const int hq = t >> 6;              // wave = h-quarter 0..3
    const int r16 = t & 15;
    const int g4 = (t >> 4) & 3;
    const int srow = t >> 4;            // 0..15 (staging row group)
    const float boutv = bout[0];

    // per-thread slice of XWx_i (+b0, *log2e), cols r16*8..+7
    float axf[8];
    {
        bf16x8 axv = *(const bf16x8*)&XWxb[i * HH + r16 * 8];
#pragma unroll
        for (int e = 0; e < 8; ++e) axf[e] = b2f((ushort_t)axv[e]);
    }
    // hoisted per-wave constants
    float4 bias1h[2];
    bias1h[0] = *(const float4*)&b1e[hq * 32 + g4 * 4];
    bias1h[1] = *(const float4*)&b1e[hq * 32 + 16 + g4 * 4];
    float4 bias2h[2];
    bias2h[0] = *(const float4*)&b2e[hq * 32 + g4 * 4];
    bias2h[1] = *(const float4*)&b2e[hq * 32 + 16 + g4 * 4];
    float4 woutr[2];
    woutr[0] = *(const float4*)&WoutE[hq * 32 + g4 * 4];
    woutr[1] = *(const float4*)&WoutE[hq * 32 + 16 + g4 * 4];

    // ---- stage both H0 tiles, interleaved ----
#pragma unroll
    for (int s = 0; s < 4; ++s) {
        const int p = s * 16 + srow;
        bf16x8 yva = *(const bf16x8*)&YWyb[(j0a + p) * HH + r16 * 8];
        bf16x8 yvb = *(const bf16x8*)&YWyb[(j0b + p) * HH + r16 * 8];
        unsigned pka[4], pkb[4];
#pragma unroll
        for (int e = 0; e < 4; ++e) {
            pka[e] = pk2(g2(axf[2 * e] + b2f((ushort_t)yva[2 * e])),
                         g2(axf[2 * e + 1] + b2f((ushort_t)yva[2 * e + 1])));
            pkb[e] = pk2(g2(axf[2 * e] + b2f((ushort_t)yvb[2 * e])),
                         g2(axf[2 * e + 1] + b2f((ushort_t)yvb[2 * e + 1])));
        }
        const int off = p * HH + ((r16 ^ (p & 7)) << 3);
        *(u32x4*)&HsA[off] = *(u32x4*)pka;
        *(u32x4*)&HsB[off] = *(u32x4*)pkb;
    }
    __syncthreads();                    // A: both H0 ready

    // ---- layer 1, both streams, shared weight fragments ----
    f32x4 accA[2][4], accB[2][4];
#pragma unroll
    for (int mt = 0; mt < 2; ++mt)
#pragma unroll
        for (int nt = 0; nt < 4; ++nt) {
            accA[mt][nt][0] = bias1h[mt].x; accA[mt][nt][1] = bias1h[mt].y;
            accA[mt][nt][2] = bias1h[mt].z; accA[mt][nt][3] = bias1h[mt].w;
            accB[mt][nt] = accA[mt][nt];
        }
#pragma unroll
    for (int ks = 0; ks < 4; ++ks) {
        const int kb = ks * 32 + g4 * 8;
        bf16x8 af0 = *(const bf16x8*)&Wt1b[(hq * 32 + r16) * HH + kb];
        bf16x8 af1 = *(const bf16x8*)&Wt1b[(hq * 32 + 16 + r16) * HH + kb];
#pragma unroll
        for (int nt = 0; nt < 4; ++nt) {
            const int j = nt * 16 + r16;
            const int off = j * HH + (kb ^ ((j & 7) << 3));
            bf16x8 bfa = *(const bf16x8*)&HsA[off];
            bf16x8 bfb = *(const bf16x8*)&HsB[off];
            accA[0][nt] = __builtin_amdgcn_mfma_f32_16x16x32_bf16(af0, bfa, accA[0][nt], 0, 0, 0);
            accB[0][nt] = __builtin_amdgcn_mfma_f32_16x16x32_bf16(af0, bfb, accB[0][nt], 0, 0, 0);
            accA[1][nt] = __builtin_amdgcn_mfma_f32_16x16x32_bf16(af1, bfa, accA[1][nt], 0, 0, 0);
            accB[1][nt] = __builtin_amdgcn_mfma_f32_16x16x32_bf16(af1, bfb, accB[1][nt], 0, 0, 0);
        }
    }
    __syncthreads();                    // R: all H0 reads retired

    // ---- store both H1 tiles in-place ----
#pragma unroll
    for (int mt = 0; mt < 2; ++mt) {
        const int hb = hq * 32 + mt * 16 + g4 * 4;
#pragma unroll
        for (int nt = 0; nt < 4; ++nt) {
            const int j = nt * 16 + r16;
            const int off = j * HH + (hb ^ ((j & 7) << 3));
            u32x2 wa, wb;
            wa[0] = pk2(g2(accA[mt][nt][0]), g2(accA[mt][nt][1]));
            wa[1] = pk2(g2(accA[mt][nt][2]), g2(accA[mt][nt][3]));
            wb[0] = pk2(g2(accB[mt][nt][0]), g2(accB[mt][nt][1]));
            wb[1] = pk2(g2(accB[mt][nt][2]), g2(accB[mt][nt][3]));
            *(u32x2*)&HsA[off] = wa;
            *(u32x2*)&HsB[off] = wb;
        }
    }
    __syncthreads();                    // X: both H1 ready

    // ---- layer 2, both streams, shared weight fragments ----
#pragma unroll
    for (int mt = 0; mt < 2; ++mt)
#pragma unroll
        for (int nt = 0; nt < 4; ++nt) {
            accA[mt][nt][0] = bias2h[mt].x; accA[mt][nt][1] = bias2h[mt].y;
            accA[mt][nt][2] = bias2h[mt].z; accA[mt][nt][3] = bias2h[mt].w;
            accB[mt][nt] = accA[mt][nt];
        }
#pragma unroll
    for (int ks = 0; ks < 4; ++ks) {
        const int kb = ks * 32 + g4 * 8;
        bf16x8 af0 = *(const bf16x8*)&Wt2b[(hq * 32 + r16) * HH + kb];
        bf16x8 af1 = *(const bf16x8*)&Wt2b[(hq * 32 + 16 + r16) * HH + kb];
#pragma unroll
        for (int nt = 0; nt < 4; ++nt) {
            const int j = nt * 16 + r16;
            const int off = j * HH + (kb ^ ((j & 7) << 3));
            bf16x8 bfa = *(const bf16x8*)&HsA[off];
            bf16x8 bfb = *(const bf16x8*)&HsB[off];
            accA[0][nt] = __builtin_amdgcn_mfma_f32_16x16x32_bf16(af0, bfa, accA[0][nt], 0, 0, 0);
            accB[0][nt] = __builtin_amdgcn_mfma_f32_16x16x32_bf16(af0, bfb, accB[0][nt], 0, 0, 0);
            accA[1][nt] = __builtin_amdgcn_mfma_f32_16x16x32_bf16(af1, bfa, accA[1][nt], 0, 0, 0);
            accB[1][nt] = __builtin_amdgcn_mfma_f32_16x16x32_bf16(af1, bfb, accB[1][nt], 0, 0, 0);
        }
    }

    // ---- epilogue in-register, both streams -> psum[stream][hq] ----
    {
        float pa[4] = {0.f, 0.f, 0.f, 0.f}, pb[4] = {0.f, 0.f, 0.f, 0.f};
#pragma unroll
        for (int mt = 0; mt < 2; ++mt) {
            const float wr[4] = {woutr[mt].x, woutr[mt].y, woutr[mt].z, woutr[mt].w};
#pragma unroll
            for (int r = 0; r < 4; ++r) {
                const float wgt = wr[r];
#pragma unroll
                for (int nt = 0; nt < 4; ++nt) {
                    pa[nt] += g2(accA[mt][nt][r]) * wgt;
                    pb[nt] += g2(accB[mt][nt][r]) * wgt;
                }
            }
        }
#pragma unroll
        for (int nt = 0; nt < 4; ++nt) {
            pa[nt] += __shfl_xor(pa[nt], 16);
            pa[nt] += __shfl_xor(pa[nt], 32);
            pb[nt] += __shfl_xor(pb[nt], 16);
            pb[nt] += __shfl_xor(pb[nt], 32);
        }
        if (g4 == 0) {
#pragma unroll
            for (int nt = 0; nt < 4; ++nt) {
                psum[0][hq][nt * 16 + r16] = pa[nt];
                psum[1][hq][nt * 16 + r16] = pb[nt];
            }
        }
    }
    __syncthreads();                    // F: psum ready

    // ---- LSE partials: waves 0,1 handle streams 0,1 (one j per lane) ----
    if (t < 128) {
        const int s2 = t >> 6;          // stream
        const int jl = t & 63;
        const float psi = boutv + psum[s2][0][jl] + psum[s2][1][jl] +
                          psum[s2][2][jl] + psum[s2][3][jl];
        const int j = q * 128 + s2 * 64 + jl;
        if (j == i) psi_arr[i] = psi;
        float cost;
        {
            const float4 u0 = *(const float4*)&U[i * RR];
            const float4 u1 = *(const float4*)&U[i * RR + 4];
            const float4 y0 = *(const float4*)&Y[j * RR];
            const float4 y1 = *(const float4*)&Y[j * RR + 4];
            cost = u0.x * y0.x + u0.y * y0.y + u0.z * y0.z + u0.w * y0.w +
                   u1.x * y1.x + u1.y * y1.y + u1.z * y1.z + u1.w * y1.w;
        }
        const float sv = cost - psi;
        float M = sv;
#pragma unroll
        for (int o = 1; o < 64; o <<= 1) M = fmaxf(M, __shfl_xor(M, o));
        float S = __builtin_amdgcn_exp2f((sv - M) * K2E);
#pragma unroll
        for (int o = 1; o < 64; o <<= 1) S += __shfl_xor(S, o);
        if (jl == 0) {
            Mp[i * 8 + q * 2 + s2] = M;
            Sp[i * 8 + q * 2 + s2] = S;
        }
    }
}

// ---- K2: combine 8 partials per i -> phi_i; total = mean(phi) + mean(psi) ----
__global__ __launch_bounds__(512) void finalize_kernel(
    const float* __restrict__ psi_arr, const float* __restrict__ Mp,
    const float* __restrict__ Sp, float* __restrict__ out) {
    __shared__ float red[8];
    const int t = threadIdx.x;  // = i
    float Mq[8], Sq[8];
#pragma unroll
    for (int q = 0; q < 8; ++q) { Mq[q] = Mp[t * 8 + q]; Sq[q] = Sp[t * 8 + q]; }
    float Mg = Mq[0];
#pragma unroll
    for (int q = 1; q < 8; ++q) Mg = fmaxf(Mg, Mq[q]);
    float S = 0.f;
#pragma unroll
    for (int q = 0; q < 8; ++q) S += Sq[q] * __builtin_amdgcn_exp2f((Mq[q] - Mg) * K2E);
    const float phi = EPSV * (__logf(S) - __logf((float)NN)) + Mg;
    float v = phi + psi_arr[t];
#pragma unroll
    for (int o = 1; o < 64; o <<= 1) v += __shfl_xor(v, o);
    if ((t & 63) == 0) red[t >> 6] = v;
    __syncthreads();
    if (t == 0) {
        float tot = 0.f;
#pragma unroll
        for (int w = 0; w < 8; ++w) tot += red[w];
        out[0] = tot / (float)NN;
    }
}

extern "C" void kernel_launch(void* const* d_in, const int* in_sizes, int n_in,
                              void* d_out, int out_size, void* d_ws, size_t ws_size,
                              hipStream_t stream) {
    (void)in_sizes; (void)n_in; (void)out_size; (void)ws_size;
    const float* X    = (const float*)d_in[0];
    const float* U    = (const float*)d_in[1];
    const float* Y    = (const float*)d_in[2];
    const float* Wx   = (const float*)d_in[3];
    const float* Wy   = (const float*)d_in[4];
    const float* b0   = (const float*)d_in[5];
    const float* W1   = (const float*)d_in[6];
    const float* b1   = (const float*)d_in[7];
    const float* W2   = (const float*)d_in[8];
    const float* b2   = (const float*)d_in[9];
    const float* Wout = (const float*)d_in[10];
    const float* bout = (const float*)d_in[11];
    float* out = (float*)d_out;

    char* ws = (char*)d_ws;
    ushort_t* Wt1b    = (ushort_t*)(ws);                   // 32 KB
    ushort_t* Wt2b    = (ushort_t*)(ws + 32768);           // 32 KB
    ushort_t* XWxb    = (ushort_t*)(ws + 65536);           // 128 KB
    ushort_t* YWyb    = (ushort_t*)(ws + 196608);          // 128 KB
    float*    psi_arr = (float*)(ws + 327680);             // 2 KB
    float*    Mp      = (float*)(ws + 329728);             // 16 KB
    float*    Sp      = (float*)(ws + 346112);             // 16 KB
    float*    b1e     = (float*)(ws + 362496);             // 512 B
    float*    b2e     = (float*)(ws + 363008);             // 512 B
    float*    WoutE   = (float*)(ws + 363520);             // 512 B

    prep_kernel<<<642, 256, 0, stream>>>(X, Y, Wx, Wy, b0, W1, W2, b1, b2, Wout,
                                         Wt1b, Wt2b, XWxb, YWyb, b1e, b2e, WoutE);
    pair_kernel<<<dim3(NN, 4), 256, 0, stream>>>(XWxb, YWyb, Wt1b, Wt2b, U, Y,
                                                 b1e, b2e, WoutE, bout, psi_arr, Mp, Sp);
    finalize_kernel<<<1, 512, 0, stream>>>(psi_arr, Mp, Sp, out);
}